// Round 6
// baseline (445.530 us; speedup 1.0000x reference)
//
#include <hip/hip_runtime.h>
#include <hip/hip_bf16.h>

#define S_LEN 2048
#define NHEAD 16
#define HDIM 64
#define EMB 1024

typedef short v8s __attribute__((ext_vector_type(8)));
typedef float v4f __attribute__((ext_vector_type(4)));

__device__ __forceinline__ float bflo(unsigned u) {
    union { unsigned u; float f; } v; v.u = u << 16; return v.f;
}
__device__ __forceinline__ float bfhi(unsigned u) {
    union { unsigned u; float f; } v; v.u = u & 0xFFFF0000u; return v.f;
}
// packed f32x2 -> bf16x2 (v_cvt_pk_bf16_f32 on gfx950), RNE
__device__ __forceinline__ unsigned cvtpk(float lo, float hi) {
    union { __hip_bfloat162 h2; unsigned u; } v;
    float2 f; f.x = lo; f.y = hi;
    v.h2 = __float22bfloat162_rn(f);
    return v.u;
}
__device__ __forceinline__ unsigned short f2bf(float f) {
    return (unsigned short)cvtpk(f, f);
}
__device__ __forceinline__ v8s cvt8(float4 a, float4 b) {
    v8s r;
    ((unsigned*)&r)[0] = cvtpk(a.x, a.y);
    ((unsigned*)&r)[1] = cvtpk(a.z, a.w);
    ((unsigned*)&r)[2] = cvtpk(b.x, b.y);
    ((unsigned*)&r)[3] = cvtpk(b.z, b.w);
    return r;
}

// ---------------------------------------------------------------------------
// K1: MFMA projections. Grid (128 s-tiles of 32, 3 tensors, 4 head-quarters),
// block = 2 waves; wave = 16 s-rows x 4 heads. 12 waves/CU (was 3 -> latency).
// Q/K: D = x @ W^T -> Qp/Kp [b][h][s][d].  V: D = W @ x^T -> Vt [b][h][d][s].
// ---------------------------------------------------------------------------
__global__ __launch_bounds__(128) void k_proj2(
    const float* __restrict__ q, const float* __restrict__ k, const float* __restrict__ v,
    const float* __restrict__ Wq, const float* __restrict__ Wk, const float* __restrict__ Wv,
    unsigned short* __restrict__ Qp, unsigned short* __restrict__ Kp, unsigned short* __restrict__ Vt)
{
    const int t = threadIdx.x, wave = t >> 6, lane = t & 63;
    const int l15 = lane & 15, l4 = lane >> 4;
    const int mtx = blockIdx.y;                    // 0:q 1:k 2:v
    const int hq = blockIdx.z;                     // head quarter
    const int row0 = blockIdx.x * 32 + wave * 16;  // global row in [0,4096)
    const int b = row0 >> 11, s0 = row0 & 2047;
    const float* X = (mtx == 0) ? q : (mtx == 1) ? k : v;
    const float* W = (mtx == 0) ? Wq : (mtx == 1) ? Wk : Wv;

    v8s wf[4][2];
    #pragma unroll
    for (int tile = 0; tile < 4; ++tile)
        #pragma unroll
        for (int c2 = 0; c2 < 2; ++c2) {
            const float* wp = W + (tile * 16 + l15) * 64 + c2 * 32 + l4 * 8;
            wf[tile][c2] = cvt8(*(const float4*)wp, *(const float4*)(wp + 4));
        }

    #pragma unroll
    for (int hi = 0; hi < 4; ++hi) {
        const int h = hq * 4 + hi;
        v8s xf[2];
        #pragma unroll
        for (int c2 = 0; c2 < 2; ++c2) {
            const float* xp = X + (size_t)(row0 + l15) * EMB + h * 64 + c2 * 32 + l4 * 8;
            xf[c2] = cvt8(*(const float4*)xp, *(const float4*)(xp + 4));
        }
        v4f acc[4];
        #pragma unroll
        for (int i = 0; i < 4; ++i) acc[i] = (v4f){0.f, 0.f, 0.f, 0.f};
        if (mtx < 2) {
            #pragma unroll
            for (int ns = 0; ns < 4; ++ns)
                #pragma unroll
                for (int c2 = 0; c2 < 2; ++c2)
                    acc[ns] = __builtin_amdgcn_mfma_f32_16x16x32_bf16(xf[c2], wf[ns][c2], acc[ns], 0, 0, 0);
            unsigned short* dst = ((mtx == 0) ? Qp : Kp) + (size_t)(b * NHEAD + h) * S_LEN * HDIM;
            #pragma unroll
            for (int ns = 0; ns < 4; ++ns)
                #pragma unroll
                for (int r = 0; r < 4; ++r)
                    dst[(size_t)(s0 + l4 * 4 + r) * HDIM + ns * 16 + l15] = f2bf(acc[ns][r]);
        } else {
            #pragma unroll
            for (int ms = 0; ms < 4; ++ms)
                #pragma unroll
                for (int c2 = 0; c2 < 2; ++c2)
                    acc[ms] = __builtin_amdgcn_mfma_f32_16x16x32_bf16(wf[ms][c2], xf[c2], acc[ms], 0, 0, 0);
            unsigned short* dst = Vt + (size_t)(b * NHEAD + h) * HDIM * S_LEN;
            #pragma unroll
            for (int ms = 0; ms < 4; ++ms)
                #pragma unroll
                for (int r = 0; r < 4; ++r)
                    dst[(size_t)(ms * 16 + l4 * 4 + r) * S_LEN + s0 + l15] = f2bf(acc[ms][r]);
        }
    }
}

// ---------------------------------------------------------------------------
// K1c: W_fc fp32 -> bf16
// ---------------------------------------------------------------------------
__global__ __launch_bounds__(256) void k_cvtw(
    const float* __restrict__ W, unsigned short* __restrict__ Wb)
{
    const int i = (blockIdx.x * 256 + threadIdx.x) * 4;
    float4 wv = *(const float4*)(W + i);
    uint2 pk;
    pk.x = cvtpk(wv.x, wv.y);
    pk.y = cvtpk(wv.z, wv.w);
    *(uint2*)(Wb + i) = pk;
}

// ---------------------------------------------------------------------------
// K2: fused attention, 2 blocks/CU. Block = 16 heads (wave w = head w) x 32 q
// x 512-wide k-quarter. Single-buffer Pex (72 KiB) + packed-bf16 Zr (4.5 KiB)
// = 78336 B LDS -> two 16-wave blocks co-resident; VGPR pinned <=64 via
// __launch_bounds__(1024,8). 3 barriers x 8 c-iters; the co-resident block
// fills each barrier drain. Swizzle id&7 -> (kq,b): one K/V set per XCD L2.
// ---------------------------------------------------------------------------
__global__ __launch_bounds__(1024, 8) void k_fattn(
    const unsigned short* __restrict__ Qp, const unsigned short* __restrict__ Kp,
    const unsigned short* __restrict__ Vt, unsigned short* __restrict__ Op)
{
    __shared__ unsigned short Pex[16][32][72];   // 72 KiB
    __shared__ unsigned ZrsU[32][36];            // 4.5 KiB, bf16x2 packed
    const int t = threadIdx.x, wave = t >> 6, lane = t & 63;
    const int l15 = lane & 15, l4 = lane >> 4;
    const int h = wave;
    const int id = blockIdx.x;
    const int slot = id & 7;
    const int kqb = slot >> 1;        // k-quarter 0..3
    const int b = slot & 1;
    const int q0 = (id >> 3) * 32;
    const unsigned short* qh = Qp + (size_t)(b * NHEAD + h) * S_LEN * HDIM;
    const unsigned short* kh = Kp + (size_t)(b * NHEAD + h) * S_LEN * HDIM;
    const unsigned short* vh = Vt + (size_t)(b * NHEAD + h) * HDIM * S_LEN;

    v8s aq[2][2];
    #pragma unroll
    for (int qs = 0; qs < 2; ++qs)
        #pragma unroll
        for (int c2 = 0; c2 < 2; ++c2)
            aq[qs][c2] = *(const v8s*)(qh + (size_t)(q0 + qs * 16 + l15) * HDIM + c2 * 32 + l4 * 8);

    v4f o[2][4];
    #pragma unroll
    for (int qs = 0; qs < 2; ++qs)
        #pragma unroll
        for (int ds = 0; ds < 4; ++ds)
            o[qs][ds] = (v4f){0.f, 0.f, 0.f, 0.f};

    const int zq = t >> 4;          // 0..31 (phase-2, t<512 only)
    const int cg = t & 15;          // col group of 4

    for (int c = 0; c < 8; ++c) {
        const int kk0 = kqb * 512 + c * 64;
        // ---- phase 1: S = Q K^T, exp -> Pex ----
        #pragma unroll
        for (int ks = 0; ks < 4; ++ks) {
            const unsigned short* kb = kh + (size_t)(kk0 + ks * 16 + l15) * HDIM + l4 * 8;
            v8s b0 = *(const v8s*)kb;
            v8s b1 = *(const v8s*)(kb + 32);
            #pragma unroll
            for (int qs = 0; qs < 2; ++qs) {
                v4f sf = (v4f){0.f, 0.f, 0.f, 0.f};
                sf = __builtin_amdgcn_mfma_f32_16x16x32_bf16(aq[qs][0], b0, sf, 0, 0, 0);
                sf = __builtin_amdgcn_mfma_f32_16x16x32_bf16(aq[qs][1], b1, sf, 0, 0, 0);
                const int rb = qs * 16 + l4 * 4;
                unsigned p01 = cvtpk(__expf(sf[0] * 0.03125f), __expf(sf[1] * 0.03125f));
                unsigned p23 = cvtpk(__expf(sf[2] * 0.03125f), __expf(sf[3] * 0.03125f));
                Pex[h][rb + 0][ks * 16 + l15] = (unsigned short)p01;
                Pex[h][rb + 1][ks * 16 + l15] = (unsigned short)(p01 >> 16);
                Pex[h][rb + 2][ks * 16 + l15] = (unsigned short)p23;
                Pex[h][rb + 3][ks * 16 + l15] = (unsigned short)(p23 >> 16);
            }
        }
        __syncthreads();
        // ---- phase 2 (waves 0-7): Zr = 1/sum_h exp, packed bf16 ----
        if (t < 512) {
            float z0 = 0.f, z1 = 0.f, z2 = 0.f, z3 = 0.f;
            #pragma unroll
            for (int hh = 0; hh < 16; ++hh) {
                uint2 u = *(const uint2*)&Pex[hh][zq][cg * 4];
                z0 += bflo(u.x); z1 += bfhi(u.x);
                z2 += bflo(u.y); z3 += bfhi(u.y);
            }
            uint2 zo;
            zo.x = cvtpk(__builtin_amdgcn_rcpf(z0), __builtin_amdgcn_rcpf(z1));
            zo.y = cvtpk(__builtin_amdgcn_rcpf(z2), __builtin_amdgcn_rcpf(z3));
            *(uint2*)&ZrsU[zq][cg * 2] = zo;
        }
        __syncthreads();
        // ---- phase 3: normalize P (A-frag order) + PV MFMA ----
        #pragma unroll
        for (int kp = 0; kp < 2; ++kp) {
            v8s bv[4];
            #pragma unroll
            for (int ds = 0; ds < 4; ++ds)
                bv[ds] = *(const v8s*)(vh + (size_t)(ds * 16 + l15) * S_LEN + kk0 + kp * 32 + l4 * 8);
            #pragma unroll
            for (int qs = 0; qs < 2; ++qs) {
                uint4 pu = *(const uint4*)&Pex[h][qs * 16 + l15][kp * 32 + l4 * 8];
                uint4 zv = *(const uint4*)&ZrsU[qs * 16 + l15][kp * 16 + l4 * 4];
                v8s pn;
                ((unsigned*)&pn)[0] = cvtpk(bflo(pu.x) * bflo(zv.x), bfhi(pu.x) * bfhi(zv.x));
                ((unsigned*)&pn)[1] = cvtpk(bflo(pu.y) * bflo(zv.y), bfhi(pu.y) * bfhi(zv.y));
                ((unsigned*)&pn)[2] = cvtpk(bflo(pu.z) * bflo(zv.z), bfhi(pu.z) * bfhi(zv.z));
                ((unsigned*)&pn)[3] = cvtpk(bflo(pu.w) * bflo(zv.w), bfhi(pu.w) * bfhi(zv.w));
                #pragma unroll
                for (int ds = 0; ds < 4; ++ds)
                    o[qs][ds] = __builtin_amdgcn_mfma_f32_16x16x32_bf16(pn, bv[ds], o[qs][ds], 0, 0, 0);
            }
        }
        __syncthreads();   // Pex/ZrsU reuse by next phase 1
    }

    // partial O plane for this (k-quarter, b), bf16
    unsigned short* op = Op + (size_t)(kqb * 2 + b) * S_LEN * EMB;
    #pragma unroll
    for (int qs = 0; qs < 2; ++qs)
        #pragma unroll
        for (int ds = 0; ds < 4; ++ds)
            #pragma unroll
            for (int r = 0; r < 4; ++r)
                op[(size_t)(q0 + qs * 16 + l4 * 4 + r) * EMB + h * 64 + ds * 16 + l15] =
                    f2bf(o[qs][ds][r]);
}

// ---------------------------------------------------------------------------
// K2b: merge the 4 k-quarter partials -> AO[b*2048+s][e] bf16
// ---------------------------------------------------------------------------
__global__ __launch_bounds__(256) void k_merge4(
    const unsigned short* __restrict__ Op, unsigned short* __restrict__ AO)
{
    const size_t i = ((size_t)blockIdx.x * 256 + threadIdx.x) * 8;
    const size_t row = i >> 10;                 // 0..4095
    const int b = (int)(row >> 11);
    const size_t off = (row & 2047) * EMB + (i & 1023);
    float a0 = 0, a1 = 0, a2 = 0, a3 = 0, a4 = 0, a5 = 0, a6 = 0, a7 = 0;
    #pragma unroll
    for (int kq = 0; kq < 4; ++kq) {
        uint4 u = *(const uint4*)(Op + (size_t)(kq * 2 + b) * S_LEN * EMB + off);
        a0 += bflo(u.x); a1 += bfhi(u.x);
        a2 += bflo(u.y); a3 += bfhi(u.y);
        a4 += bflo(u.z); a5 += bfhi(u.z);
        a6 += bflo(u.w); a7 += bfhi(u.w);
    }
    uint4 r;
    r.x = cvtpk(a0, a1); r.y = cvtpk(a2, a3);
    r.z = cvtpk(a4, a5); r.w = cvtpk(a6, a7);
    *(uint4*)(AO + i) = r;
}

// ---------------------------------------------------------------------------
// K4: out = AO @ W_fc^T + b_fc   (M=4096, N=1024, K=1024), fp32 out
// ---------------------------------------------------------------------------
__global__ __launch_bounds__(256) void k_fc(
    const unsigned short* __restrict__ AO, const unsigned short* __restrict__ Wb,
    const float* __restrict__ bias, float* __restrict__ out)
{
    const int t = threadIdx.x, wave = t >> 6, lane = t & 63;
    const int l15 = lane & 15, l4 = lane >> 4;
    const int m0 = blockIdx.x * 64 + wave * 16;
    const int n0 = blockIdx.y * 64;
    v4f c[4];
    #pragma unroll
    for (int i = 0; i < 4; ++i) c[i] = (v4f){0.f, 0.f, 0.f, 0.f};
    for (int k = 0; k < EMB; k += 32) {
        v8s a = *(const v8s*)(AO + (size_t)(m0 + l15) * EMB + k + l4 * 8);
        #pragma unroll
        for (int ns = 0; ns < 4; ++ns) {
            v8s bw = *(const v8s*)(Wb + (size_t)(n0 + ns * 16 + l15) * EMB + k + l4 * 8);
            c[ns] = __builtin_amdgcn_mfma_f32_16x16x32_bf16(a, bw, c[ns], 0, 0, 0);
        }
    }
    #pragma unroll
    for (int ns = 0; ns < 4; ++ns) {
        const float bv = bias[n0 + ns * 16 + l15];
        #pragma unroll
        for (int r = 0; r < 4; ++r)
            out[(size_t)(m0 + l4 * 4 + r) * EMB + n0 + ns * 16 + l15] = c[ns][r] + bv;
    }
}

extern "C" void kernel_launch(void* const* d_in, const int* in_sizes, int n_in,
                              void* d_out, int out_size, void* d_ws, size_t ws_size,
                              hipStream_t stream)
{
    (void)in_sizes; (void)n_in; (void)out_size; (void)ws_size;
    const float* q   = (const float*)d_in[0];
    const float* k   = (const float*)d_in[1];
    const float* v   = (const float*)d_in[2];
    const float* Wq  = (const float*)d_in[3];
    const float* Wk  = (const float*)d_in[4];
    const float* Wv  = (const float*)d_in[5];
    const float* Wfc = (const float*)d_in[6];
    const float* bfc = (const float*)d_in[7];

    char* w = (char*)d_ws;
    unsigned short* Qp = (unsigned short*)(w);                      //  8 MiB (AO overlays after k_fattn)
    unsigned short* Kp = (unsigned short*)(w + (8u  << 20));        //  8 MiB
    unsigned short* Vt = (unsigned short*)(w + (16u << 20));        //  8 MiB
    unsigned short* Wb = (unsigned short*)(w + (24u << 20));        //  2 MiB
    unsigned short* Op = (unsigned short*)(w + (26u << 20));        // 32 MiB (8 planes)
    unsigned short* AO = Qp;                                        // reuse (Qp dead post-attn)

    k_proj2 <<<dim3(128, 3, 4), dim3(128),  0, stream>>>(q, k, v, Wq, Wk, Wv, Qp, Kp, Vt);
    k_cvtw  <<<dim3(1024),      dim3(256),  0, stream>>>(Wfc, Wb);
    k_fattn <<<dim3(512),       dim3(1024), 0, stream>>>(Qp, Kp, Vt, Op);
    k_merge4<<<dim3(2048),      dim3(256),  0, stream>>>(Op, AO);
    k_fc    <<<dim3(64, 16),    dim3(256),  0, stream>>>(AO, Wb, bfc, (float*)d_out);
}

// Round 7
// 320.452 us; speedup vs baseline: 1.3903x; 1.3903x over previous
//
#include <hip/hip_runtime.h>
#include <hip/hip_bf16.h>

#define S_LEN 2048
#define NHEAD 16
#define HDIM 64
#define EMB 1024

typedef short v8s __attribute__((ext_vector_type(8)));
typedef float v4f __attribute__((ext_vector_type(4)));

__device__ __forceinline__ float bflo(unsigned u) {
    union { unsigned u; float f; } v; v.u = u << 16; return v.f;
}
__device__ __forceinline__ float bfhi(unsigned u) {
    union { unsigned u; float f; } v; v.u = u & 0xFFFF0000u; return v.f;
}
// packed f32x2 -> bf16x2 (v_cvt_pk_bf16_f32 on gfx950), RNE
__device__ __forceinline__ unsigned cvtpk(float lo, float hi) {
    union { __hip_bfloat162 h2; unsigned u; } v;
    float2 f; f.x = lo; f.y = hi;
    v.h2 = __float22bfloat162_rn(f);
    return v.u;
}
__device__ __forceinline__ unsigned short f2bf(float f) {
    return (unsigned short)cvtpk(f, f);
}
__device__ __forceinline__ v8s cvt8(float4 a, float4 b) {
    v8s r;
    ((unsigned*)&r)[0] = cvtpk(a.x, a.y);
    ((unsigned*)&r)[1] = cvtpk(a.z, a.w);
    ((unsigned*)&r)[2] = cvtpk(b.x, b.y);
    ((unsigned*)&r)[3] = cvtpk(b.z, b.w);
    return r;
}

// ---------------------------------------------------------------------------
// K1: MFMA projections. Grid (128 s-tiles of 32, 3 tensors, 4 head-quarters),
// block = 2 waves; wave = 16 s-rows x 4 heads.
// Q/K: D = x @ W^T -> Qp/Kp [b][h][s][d].  V: D = W @ x^T -> Vt [b][h][d][s].
// ---------------------------------------------------------------------------
__global__ __launch_bounds__(128) void k_proj2(
    const float* __restrict__ q, const float* __restrict__ k, const float* __restrict__ v,
    const float* __restrict__ Wq, const float* __restrict__ Wk, const float* __restrict__ Wv,
    unsigned short* __restrict__ Qp, unsigned short* __restrict__ Kp, unsigned short* __restrict__ Vt)
{
    const int t = threadIdx.x, wave = t >> 6, lane = t & 63;
    const int l15 = lane & 15, l4 = lane >> 4;
    const int mtx = blockIdx.y;                    // 0:q 1:k 2:v
    const int hq = blockIdx.z;                     // head quarter
    const int row0 = blockIdx.x * 32 + wave * 16;  // global row in [0,4096)
    const int b = row0 >> 11, s0 = row0 & 2047;
    const float* X = (mtx == 0) ? q : (mtx == 1) ? k : v;
    const float* W = (mtx == 0) ? Wq : (mtx == 1) ? Wk : Wv;

    v8s wf[4][2];
    #pragma unroll
    for (int tile = 0; tile < 4; ++tile)
        #pragma unroll
        for (int c2 = 0; c2 < 2; ++c2) {
            const float* wp = W + (tile * 16 + l15) * 64 + c2 * 32 + l4 * 8;
            wf[tile][c2] = cvt8(*(const float4*)wp, *(const float4*)(wp + 4));
        }

    #pragma unroll
    for (int hi = 0; hi < 4; ++hi) {
        const int h = hq * 4 + hi;
        v8s xf[2];
        #pragma unroll
        for (int c2 = 0; c2 < 2; ++c2) {
            const float* xp = X + (size_t)(row0 + l15) * EMB + h * 64 + c2 * 32 + l4 * 8;
            xf[c2] = cvt8(*(const float4*)xp, *(const float4*)(xp + 4));
        }
        v4f acc[4];
        #pragma unroll
        for (int i = 0; i < 4; ++i) acc[i] = (v4f){0.f, 0.f, 0.f, 0.f};
        if (mtx < 2) {
            #pragma unroll
            for (int ns = 0; ns < 4; ++ns)
                #pragma unroll
                for (int c2 = 0; c2 < 2; ++c2)
                    acc[ns] = __builtin_amdgcn_mfma_f32_16x16x32_bf16(xf[c2], wf[ns][c2], acc[ns], 0, 0, 0);
            unsigned short* dst = ((mtx == 0) ? Qp : Kp) + (size_t)(b * NHEAD + h) * S_LEN * HDIM;
            #pragma unroll
            for (int ns = 0; ns < 4; ++ns)
                #pragma unroll
                for (int r = 0; r < 4; ++r)
                    dst[(size_t)(s0 + l4 * 4 + r) * HDIM + ns * 16 + l15] = f2bf(acc[ns][r]);
        } else {
            #pragma unroll
            for (int ms = 0; ms < 4; ++ms)
                #pragma unroll
                for (int c2 = 0; c2 < 2; ++c2)
                    acc[ms] = __builtin_amdgcn_mfma_f32_16x16x32_bf16(wf[ms][c2], xf[c2], acc[ms], 0, 0, 0);
            unsigned short* dst = Vt + (size_t)(b * NHEAD + h) * HDIM * S_LEN;
            #pragma unroll
            for (int ms = 0; ms < 4; ++ms)
                #pragma unroll
                for (int r = 0; r < 4; ++r)
                    dst[(size_t)(ms * 16 + l4 * 4 + r) * S_LEN + s0 + l15] = f2bf(acc[ms][r]);
        }
    }
}

// ---------------------------------------------------------------------------
// K1c: W_fc fp32 -> bf16
// ---------------------------------------------------------------------------
__global__ __launch_bounds__(256) void k_cvtw(
    const float* __restrict__ W, unsigned short* __restrict__ Wb)
{
    const int i = (blockIdx.x * 256 + threadIdx.x) * 4;
    float4 wv = *(const float4*)(W + i);
    uint2 pk;
    pk.x = cvtpk(wv.x, wv.y);
    pk.y = cvtpk(wv.z, wv.w);
    *(uint2*)(Wb + i) = pk;
}

// ---------------------------------------------------------------------------
// K2: fused attention, 2 blocks/CU. Block = 16 heads (wave w = head w) x 32 q
// x 512-wide k-quarter. Single-buffer Pex (72 KiB) + packed-bf16 Zr (4.5 KiB)
// = 78336 B LDS -> two 16-wave blocks co-resident. __launch_bounds__(1024,4):
// R6's (1024,8) forced VGPR=32 -> scratch spills (805 MB HBM, 259 us). (1024,4)
// compiles ~52 VGPR <= 64, so 2 blocks fit without spilling.
// Pex is wave-private -> only 2 barriers per c-iter needed (phase-2 cross-head
// reduce in, ZrsU out); next-iter overwrites are provably ordered by them.
// Swizzle id&7 -> (kq,b): one 2 MB K/V working set per XCD L2.
// ---------------------------------------------------------------------------
__global__ __launch_bounds__(1024, 4) void k_fattn(
    const unsigned short* __restrict__ Qp, const unsigned short* __restrict__ Kp,
    const unsigned short* __restrict__ Vt, unsigned short* __restrict__ Op)
{
    __shared__ unsigned short Pex[16][32][72];   // 72 KiB
    __shared__ unsigned ZrsU[32][36];            // 4.5 KiB, bf16x2 packed
    const int t = threadIdx.x, wave = t >> 6, lane = t & 63;
    const int l15 = lane & 15, l4 = lane >> 4;
    const int h = wave;
    const int id = blockIdx.x;
    const int slot = id & 7;
    const int kqb = slot >> 1;        // k-quarter 0..3
    const int b = slot & 1;
    const int q0 = (id >> 3) * 32;
    const unsigned short* qh = Qp + (size_t)(b * NHEAD + h) * S_LEN * HDIM;
    const unsigned short* kh = Kp + (size_t)(b * NHEAD + h) * S_LEN * HDIM;
    const unsigned short* vh = Vt + (size_t)(b * NHEAD + h) * HDIM * S_LEN;

    v8s aq[2][2];
    #pragma unroll
    for (int qs = 0; qs < 2; ++qs)
        #pragma unroll
        for (int c2 = 0; c2 < 2; ++c2)
            aq[qs][c2] = *(const v8s*)(qh + (size_t)(q0 + qs * 16 + l15) * HDIM + c2 * 32 + l4 * 8);

    v4f o[2][4];
    #pragma unroll
    for (int qs = 0; qs < 2; ++qs)
        #pragma unroll
        for (int ds = 0; ds < 4; ++ds)
            o[qs][ds] = (v4f){0.f, 0.f, 0.f, 0.f};

    const int zq = t >> 4;          // 0..31 (phase-2, t<512 only)
    const int cg = t & 15;          // col group of 4

    for (int c = 0; c < 8; ++c) {
        const int kk0 = kqb * 512 + c * 64;
        // ---- phase 1: S = Q K^T, exp -> Pex (wave-private plane) ----
        #pragma unroll
        for (int ks = 0; ks < 4; ++ks) {
            const unsigned short* kb = kh + (size_t)(kk0 + ks * 16 + l15) * HDIM + l4 * 8;
            v8s b0 = *(const v8s*)kb;
            v8s b1 = *(const v8s*)(kb + 32);
            #pragma unroll
            for (int qs = 0; qs < 2; ++qs) {
                v4f sf = (v4f){0.f, 0.f, 0.f, 0.f};
                sf = __builtin_amdgcn_mfma_f32_16x16x32_bf16(aq[qs][0], b0, sf, 0, 0, 0);
                sf = __builtin_amdgcn_mfma_f32_16x16x32_bf16(aq[qs][1], b1, sf, 0, 0, 0);
                const int rb = qs * 16 + l4 * 4;
                unsigned p01 = cvtpk(__expf(sf[0] * 0.03125f), __expf(sf[1] * 0.03125f));
                unsigned p23 = cvtpk(__expf(sf[2] * 0.03125f), __expf(sf[3] * 0.03125f));
                Pex[h][rb + 0][ks * 16 + l15] = (unsigned short)p01;
                Pex[h][rb + 1][ks * 16 + l15] = (unsigned short)(p01 >> 16);
                Pex[h][rb + 2][ks * 16 + l15] = (unsigned short)p23;
                Pex[h][rb + 3][ks * 16 + l15] = (unsigned short)(p23 >> 16);
            }
        }
        __syncthreads();
        // ---- phase 2 (waves 0-7): Zr = 1/sum_h exp, packed bf16 ----
        if (t < 512) {
            float z0 = 0.f, z1 = 0.f, z2 = 0.f, z3 = 0.f;
            #pragma unroll
            for (int hh = 0; hh < 16; ++hh) {
                uint2 u = *(const uint2*)&Pex[hh][zq][cg * 4];
                z0 += bflo(u.x); z1 += bfhi(u.x);
                z2 += bflo(u.y); z3 += bfhi(u.y);
            }
            uint2 zo;
            zo.x = cvtpk(__builtin_amdgcn_rcpf(z0), __builtin_amdgcn_rcpf(z1));
            zo.y = cvtpk(__builtin_amdgcn_rcpf(z2), __builtin_amdgcn_rcpf(z3));
            *(uint2*)&ZrsU[zq][cg * 2] = zo;
        }
        __syncthreads();
        // ---- phase 3: normalize P (A-frag order) + PV MFMA ----
        #pragma unroll
        for (int kp = 0; kp < 2; ++kp) {
            v8s bv[4];
            #pragma unroll
            for (int ds = 0; ds < 4; ++ds)
                bv[ds] = *(const v8s*)(vh + (size_t)(ds * 16 + l15) * S_LEN + kk0 + kp * 32 + l4 * 8);
            #pragma unroll
            for (int qs = 0; qs < 2; ++qs) {
                uint4 pu = *(const uint4*)&Pex[h][qs * 16 + l15][kp * 32 + l4 * 8];
                uint4 zv = *(const uint4*)&ZrsU[qs * 16 + l15][kp * 16 + l4 * 4];
                v8s pn;
                ((unsigned*)&pn)[0] = cvtpk(bflo(pu.x) * bflo(zv.x), bfhi(pu.x) * bfhi(zv.x));
                ((unsigned*)&pn)[1] = cvtpk(bflo(pu.y) * bflo(zv.y), bfhi(pu.y) * bfhi(zv.y));
                ((unsigned*)&pn)[2] = cvtpk(bflo(pu.z) * bflo(zv.z), bfhi(pu.z) * bfhi(zv.z));
                ((unsigned*)&pn)[3] = cvtpk(bflo(pu.w) * bflo(zv.w), bfhi(pu.w) * bfhi(zv.w));
                #pragma unroll
                for (int ds = 0; ds < 4; ++ds)
                    o[qs][ds] = __builtin_amdgcn_mfma_f32_16x16x32_bf16(pn, bv[ds], o[qs][ds], 0, 0, 0);
            }
        }
        // no 3rd barrier: Pex[h] is wave-private; ZrsU rewrite is ordered by
        // the next iteration's two barriers.
    }

    // partial O plane for this (k-quarter, b), bf16
    unsigned short* op = Op + (size_t)(kqb * 2 + b) * S_LEN * EMB;
    #pragma unroll
    for (int qs = 0; qs < 2; ++qs)
        #pragma unroll
        for (int ds = 0; ds < 4; ++ds)
            #pragma unroll
            for (int r = 0; r < 4; ++r)
                op[(size_t)(q0 + qs * 16 + l4 * 4 + r) * EMB + h * 64 + ds * 16 + l15] =
                    f2bf(o[qs][ds][r]);
}

// ---------------------------------------------------------------------------
// K2b: merge the 4 k-quarter partials -> AO[b*2048+s][e] bf16
// ---------------------------------------------------------------------------
__global__ __launch_bounds__(256) void k_merge4(
    const unsigned short* __restrict__ Op, unsigned short* __restrict__ AO)
{
    const size_t i = ((size_t)blockIdx.x * 256 + threadIdx.x) * 8;
    const size_t row = i >> 10;                 // 0..4095
    const int b = (int)(row >> 11);
    const size_t off = (row & 2047) * EMB + (i & 1023);
    float a0 = 0, a1 = 0, a2 = 0, a3 = 0, a4 = 0, a5 = 0, a6 = 0, a7 = 0;
    #pragma unroll
    for (int kq = 0; kq < 4; ++kq) {
        uint4 u = *(const uint4*)(Op + (size_t)(kq * 2 + b) * S_LEN * EMB + off);
        a0 += bflo(u.x); a1 += bfhi(u.x);
        a2 += bflo(u.y); a3 += bfhi(u.y);
        a4 += bflo(u.z); a5 += bfhi(u.z);
        a6 += bflo(u.w); a7 += bfhi(u.w);
    }
    uint4 r;
    r.x = cvtpk(a0, a1); r.y = cvtpk(a2, a3);
    r.z = cvtpk(a4, a5); r.w = cvtpk(a6, a7);
    *(uint4*)(AO + i) = r;
}

// ---------------------------------------------------------------------------
// K4: out = AO @ W_fc^T + b_fc   (M=4096, N=1024, K=1024), fp32 out.
// Wave = 32 m-rows x 64 n-cols: 2 A-loads share each set of 4 B-loads.
// ---------------------------------------------------------------------------
__global__ __launch_bounds__(256) void k_fc(
    const unsigned short* __restrict__ AO, const unsigned short* __restrict__ Wb,
    const float* __restrict__ bias, float* __restrict__ out)
{
    const int t = threadIdx.x, wave = t >> 6, lane = t & 63;
    const int l15 = lane & 15, l4 = lane >> 4;
    const int m0 = blockIdx.x * 128 + wave * 32;
    const int n0 = blockIdx.y * 64;
    v4f c[2][4];
    #pragma unroll
    for (int i = 0; i < 2; ++i)
        #pragma unroll
        for (int j = 0; j < 4; ++j) c[i][j] = (v4f){0.f, 0.f, 0.f, 0.f};
    for (int k = 0; k < EMB; k += 32) {
        v8s a0 = *(const v8s*)(AO + (size_t)(m0 + l15) * EMB + k + l4 * 8);
        v8s a1 = *(const v8s*)(AO + (size_t)(m0 + 16 + l15) * EMB + k + l4 * 8);
        #pragma unroll
        for (int ns = 0; ns < 4; ++ns) {
            v8s bw = *(const v8s*)(Wb + (size_t)(n0 + ns * 16 + l15) * EMB + k + l4 * 8);
            c[0][ns] = __builtin_amdgcn_mfma_f32_16x16x32_bf16(a0, bw, c[0][ns], 0, 0, 0);
            c[1][ns] = __builtin_amdgcn_mfma_f32_16x16x32_bf16(a1, bw, c[1][ns], 0, 0, 0);
        }
    }
    #pragma unroll
    for (int ms = 0; ms < 2; ++ms)
        #pragma unroll
        for (int ns = 0; ns < 4; ++ns) {
            const float bv = bias[n0 + ns * 16 + l15];
            #pragma unroll
            for (int r = 0; r < 4; ++r)
                out[(size_t)(m0 + ms * 16 + l4 * 4 + r) * EMB + n0 + ns * 16 + l15] = c[ms][ns][r] + bv;
        }
}

extern "C" void kernel_launch(void* const* d_in, const int* in_sizes, int n_in,
                              void* d_out, int out_size, void* d_ws, size_t ws_size,
                              hipStream_t stream)
{
    (void)in_sizes; (void)n_in; (void)out_size; (void)ws_size;
    const float* q   = (const float*)d_in[0];
    const float* k   = (const float*)d_in[1];
    const float* v   = (const float*)d_in[2];
    const float* Wq  = (const float*)d_in[3];
    const float* Wk  = (const float*)d_in[4];
    const float* Wv  = (const float*)d_in[5];
    const float* Wfc = (const float*)d_in[6];
    const float* bfc = (const float*)d_in[7];

    char* w = (char*)d_ws;
    unsigned short* Qp = (unsigned short*)(w);                      //  8 MiB (AO overlays after k_fattn)
    unsigned short* Kp = (unsigned short*)(w + (8u  << 20));        //  8 MiB
    unsigned short* Vt = (unsigned short*)(w + (16u << 20));        //  8 MiB
    unsigned short* Wb = (unsigned short*)(w + (24u << 20));        //  2 MiB
    unsigned short* Op = (unsigned short*)(w + (26u << 20));        // 32 MiB (8 planes)
    unsigned short* AO = Qp;                                        // reuse (Qp dead post-attn)

    k_proj2 <<<dim3(128, 3, 4), dim3(128),  0, stream>>>(q, k, v, Wq, Wk, Wv, Qp, Kp, Vt);
    k_cvtw  <<<dim3(1024),      dim3(256),  0, stream>>>(Wfc, Wb);
    k_fattn <<<dim3(512),       dim3(1024), 0, stream>>>(Qp, Kp, Vt, Op);
    k_merge4<<<dim3(2048),      dim3(256),  0, stream>>>(Op, AO);
    k_fc    <<<dim3(32, 16),    dim3(256),  0, stream>>>(AO, Wb, bfc, (float*)d_out);
}

// Round 8
// 277.731 us; speedup vs baseline: 1.6042x; 1.1538x over previous
//
#include <hip/hip_runtime.h>
#include <hip/hip_bf16.h>

#define S_LEN 2048
#define NHEAD 16
#define HDIM 64
#define EMB 1024

typedef short v8s __attribute__((ext_vector_type(8)));
typedef float v4f __attribute__((ext_vector_type(4)));

__device__ __forceinline__ float bflo(unsigned u) {
    union { unsigned u; float f; } v; v.u = u << 16; return v.f;
}
__device__ __forceinline__ float bfhi(unsigned u) {
    union { unsigned u; float f; } v; v.u = u & 0xFFFF0000u; return v.f;
}
// packed f32x2 -> bf16x2 (v_cvt_pk_bf16_f32 on gfx950), RNE
__device__ __forceinline__ unsigned cvtpk(float lo, float hi) {
    union { __hip_bfloat162 h2; unsigned u; } v;
    float2 f; f.x = lo; f.y = hi;
    v.h2 = __float22bfloat162_rn(f);
    return v.u;
}
__device__ __forceinline__ unsigned short f2bf(float f) {
    return (unsigned short)cvtpk(f, f);
}
__device__ __forceinline__ v8s cvt8(float4 a, float4 b) {
    v8s r;
    ((unsigned*)&r)[0] = cvtpk(a.x, a.y);
    ((unsigned*)&r)[1] = cvtpk(a.z, a.w);
    ((unsigned*)&r)[2] = cvtpk(b.x, b.y);
    ((unsigned*)&r)[3] = cvtpk(b.z, b.w);
    return r;
}

// ---------------------------------------------------------------------------
// K1: MFMA projections. Grid (128 s-tiles of 32, 3 tensors, 4 head-quarters),
// block = 2 waves; wave = 16 s-rows x 4 heads.
// Q/K: D = x @ W^T -> Qp/Kp [b][h][s][d], stores staged through a wave-private
// LDS tile so the global write is coalesced dwordx4 (the C-fragment layout
// would otherwise scatter 2B stores across 16 lines per instruction).
// V: D = W @ x^T -> Vt [b][h][d][s].
// ---------------------------------------------------------------------------
__global__ __launch_bounds__(128) void k_proj2(
    const float* __restrict__ q, const float* __restrict__ k, const float* __restrict__ v,
    const float* __restrict__ Wq, const float* __restrict__ Wk, const float* __restrict__ Wv,
    unsigned short* __restrict__ Qp, unsigned short* __restrict__ Kp, unsigned short* __restrict__ Vt)
{
    __shared__ unsigned short Tq[2][16][72];       // wave-private bounce tiles
    const int t = threadIdx.x, wave = t >> 6, lane = t & 63;
    const int l15 = lane & 15, l4 = lane >> 4;
    const int mtx = blockIdx.y;                    // 0:q 1:k 2:v
    const int hq = blockIdx.z;                     // head quarter
    const int row0 = blockIdx.x * 32 + wave * 16;  // global row in [0,4096)
    const int b = row0 >> 11, s0 = row0 & 2047;
    const float* X = (mtx == 0) ? q : (mtx == 1) ? k : v;
    const float* W = (mtx == 0) ? Wq : (mtx == 1) ? Wk : Wv;

    v8s wf[4][2];
    #pragma unroll
    for (int tile = 0; tile < 4; ++tile)
        #pragma unroll
        for (int c2 = 0; c2 < 2; ++c2) {
            const float* wp = W + (tile * 16 + l15) * 64 + c2 * 32 + l4 * 8;
            wf[tile][c2] = cvt8(*(const float4*)wp, *(const float4*)(wp + 4));
        }

    #pragma unroll
    for (int hi = 0; hi < 4; ++hi) {
        const int h = hq * 4 + hi;
        v8s xf[2];
        #pragma unroll
        for (int c2 = 0; c2 < 2; ++c2) {
            const float* xp = X + (size_t)(row0 + l15) * EMB + h * 64 + c2 * 32 + l4 * 8;
            xf[c2] = cvt8(*(const float4*)xp, *(const float4*)(xp + 4));
        }
        v4f acc[4];
        #pragma unroll
        for (int i = 0; i < 4; ++i) acc[i] = (v4f){0.f, 0.f, 0.f, 0.f};
        if (mtx < 2) {
            #pragma unroll
            for (int ns = 0; ns < 4; ++ns)
                #pragma unroll
                for (int c2 = 0; c2 < 2; ++c2)
                    acc[ns] = __builtin_amdgcn_mfma_f32_16x16x32_bf16(xf[c2], wf[ns][c2], acc[ns], 0, 0, 0);
            // stage C-frags (col=l15, rows l4*4+r) in LDS, wave-private
            #pragma unroll
            for (int ns = 0; ns < 4; ++ns)
                #pragma unroll
                for (int r = 0; r < 4; ++r)
                    Tq[wave][l4 * 4 + r][ns * 16 + l15] = f2bf(acc[ns][r]);
            // read back row-major, coalesced global store (lgkmcnt auto)
            const int row = lane >> 2, c8 = (lane & 3) * 16;
            uint4 d0 = *(const uint4*)&Tq[wave][row][c8];
            uint4 d1 = *(const uint4*)&Tq[wave][row][c8 + 8];
            unsigned short* dst = ((mtx == 0) ? Qp : Kp)
                + (size_t)(b * NHEAD + h) * S_LEN * HDIM + (size_t)(s0 + row) * HDIM + c8;
            *(uint4*)dst = d0;
            *(uint4*)(dst + 8) = d1;
        } else {
            #pragma unroll
            for (int ms = 0; ms < 4; ++ms)
                #pragma unroll
                for (int c2 = 0; c2 < 2; ++c2)
                    acc[ms] = __builtin_amdgcn_mfma_f32_16x16x32_bf16(wf[ms][c2], xf[c2], acc[ms], 0, 0, 0);
            unsigned short* dst = Vt + (size_t)(b * NHEAD + h) * HDIM * S_LEN;
            #pragma unroll
            for (int ms = 0; ms < 4; ++ms)
                #pragma unroll
                for (int r = 0; r < 4; ++r)
                    dst[(size_t)(ms * 16 + l4 * 4 + r) * S_LEN + s0 + l15] = f2bf(acc[ms][r]);
        }
    }
}

// ---------------------------------------------------------------------------
// K1c: W_fc fp32 -> bf16
// ---------------------------------------------------------------------------
__global__ __launch_bounds__(256) void k_cvtw(
    const float* __restrict__ W, unsigned short* __restrict__ Wb)
{
    const int i = (blockIdx.x * 256 + threadIdx.x) * 4;
    float4 wv = *(const float4*)(W + i);
    uint2 pk;
    pk.x = cvtpk(wv.x, wv.y);
    pk.y = cvtpk(wv.z, wv.w);
    *(uint2*)(Wb + i) = pk;
}

// ---------------------------------------------------------------------------
// K2: fused attention, qT=64 (doubled reuse: K/V cache traffic 2 GB -> 0.6 GB;
// all prior ~150us variants were cache-BW-bound at ~2 GB). Block = 16 heads
// (wave w = head w) x 64 q rows x 512-wide k-quarter; k-chunk 32 per c-iter.
// LDS: Pex[16][64][40] 80 KiB + Zr 5 KiB -> 1 block/CU, 16 waves.
// Swizzle id&7 -> (kq, b): one 2 MB K/V working set per XCD L2.
// VGPR target ~125 under the (1024,4) cap=128 (spill watch: WRITE_SIZE).
// ---------------------------------------------------------------------------
__global__ __launch_bounds__(1024, 4) void k_fattn(
    const unsigned short* __restrict__ Qp, const unsigned short* __restrict__ Kp,
    const unsigned short* __restrict__ Vt, unsigned short* __restrict__ Op)
{
    __shared__ unsigned short Pex[16][64][40];   // 80 KiB (rows 80B: 16B-aligned)
    __shared__ unsigned ZrsU[64][20];            // 5 KiB, bf16x2 packed, 80B rows
    const int t = threadIdx.x, wave = t >> 6, lane = t & 63;
    const int l15 = lane & 15, l4 = lane >> 4;
    const int h = wave;
    const int id = blockIdx.x;
    const int slot = id & 7;
    const int kqb = slot & 3;         // k-quarter 0..3
    const int bsel = slot >> 2;       // batch
    const int qt = bsel * 32 + (id >> 3);   // q-tile of 64 rows, 0..63
    const int b = qt >> 5;
    const int q0 = (qt & 31) * 64;          // s-offset within batch
    const unsigned short* qh = Qp + (size_t)(b * NHEAD + h) * S_LEN * HDIM;
    const unsigned short* kh = Kp + (size_t)(b * NHEAD + h) * S_LEN * HDIM;
    const unsigned short* vh = Vt + (size_t)(b * NHEAD + h) * HDIM * S_LEN;

    v8s aq[4][2];
    #pragma unroll
    for (int qs = 0; qs < 4; ++qs)
        #pragma unroll
        for (int c2 = 0; c2 < 2; ++c2)
            aq[qs][c2] = *(const v8s*)(qh + (size_t)(q0 + qs * 16 + l15) * HDIM + c2 * 32 + l4 * 8);

    v4f o[4][4];
    #pragma unroll
    for (int qs = 0; qs < 4; ++qs)
        #pragma unroll
        for (int ds = 0; ds < 4; ++ds)
            o[qs][ds] = (v4f){0.f, 0.f, 0.f, 0.f};

    const int zq = t >> 4;          // 0..63: q row for Z-reduce
    const int zc = t & 15;          // col-pair index (2 cols each)

    for (int c = 0; c < 16; ++c) {
        const int kk0 = kqb * 512 + c * 32;
        // ---- phase 1: S = Q K^T (64q x 32k), exp -> Pex (wave-private plane)
        #pragma unroll
        for (int ks = 0; ks < 2; ++ks) {
            const unsigned short* kb = kh + (size_t)(kk0 + ks * 16 + l15) * HDIM + l4 * 8;
            v8s b0 = *(const v8s*)kb;
            v8s b1 = *(const v8s*)(kb + 32);
            #pragma unroll
            for (int qs = 0; qs < 4; ++qs) {
                v4f sf = (v4f){0.f, 0.f, 0.f, 0.f};
                sf = __builtin_amdgcn_mfma_f32_16x16x32_bf16(aq[qs][0], b0, sf, 0, 0, 0);
                sf = __builtin_amdgcn_mfma_f32_16x16x32_bf16(aq[qs][1], b1, sf, 0, 0, 0);
                const int rb = qs * 16 + l4 * 4;
                unsigned p01 = cvtpk(__expf(sf[0] * 0.03125f), __expf(sf[1] * 0.03125f));
                unsigned p23 = cvtpk(__expf(sf[2] * 0.03125f), __expf(sf[3] * 0.03125f));
                Pex[h][rb + 0][ks * 16 + l15] = (unsigned short)p01;
                Pex[h][rb + 1][ks * 16 + l15] = (unsigned short)(p01 >> 16);
                Pex[h][rb + 2][ks * 16 + l15] = (unsigned short)p23;
                Pex[h][rb + 3][ks * 16 + l15] = (unsigned short)(p23 >> 16);
            }
        }
        __syncthreads();
        // ---- phase 2 (all 1024 threads): Zr = 1/sum_h exp, packed bf16 ----
        {
            float z0 = 0.f, z1 = 0.f;
            #pragma unroll
            for (int hh = 0; hh < 16; ++hh) {
                unsigned u = *(const unsigned*)&Pex[hh][zq][zc * 2];
                z0 += bflo(u); z1 += bfhi(u);
            }
            ZrsU[zq][zc] = cvtpk(__builtin_amdgcn_rcpf(z0), __builtin_amdgcn_rcpf(z1));
        }
        __syncthreads();
        // ---- phase 3: normalize P (A-frag order) + PV MFMA (k=32) ----
        {
            v8s bv[4];
            #pragma unroll
            for (int ds = 0; ds < 4; ++ds)
                bv[ds] = *(const v8s*)(vh + (size_t)(ds * 16 + l15) * S_LEN + kk0 + l4 * 8);
            #pragma unroll
            for (int qs = 0; qs < 4; ++qs) {
                uint4 pu = *(const uint4*)&Pex[h][qs * 16 + l15][l4 * 8];
                uint4 zv = *(const uint4*)&ZrsU[qs * 16 + l15][l4 * 4];
                v8s pn;
                ((unsigned*)&pn)[0] = cvtpk(bflo(pu.x) * bflo(zv.x), bfhi(pu.x) * bfhi(zv.x));
                ((unsigned*)&pn)[1] = cvtpk(bflo(pu.y) * bflo(zv.y), bfhi(pu.y) * bfhi(zv.y));
                ((unsigned*)&pn)[2] = cvtpk(bflo(pu.z) * bflo(zv.z), bfhi(pu.z) * bfhi(zv.z));
                ((unsigned*)&pn)[3] = cvtpk(bflo(pu.w) * bflo(zv.w), bfhi(pu.w) * bfhi(zv.w));
                #pragma unroll
                for (int ds = 0; ds < 4; ++ds)
                    o[qs][ds] = __builtin_amdgcn_mfma_f32_16x16x32_bf16(pn, bv[ds], o[qs][ds], 0, 0, 0);
            }
        }
        // no 3rd barrier: Pex[h] is wave-private; ZrsU rewrite ordered by the
        // next iteration's two barriers.
    }

    // partial O plane for this (k-quarter, b), bf16
    unsigned short* op = Op + (size_t)(kqb * 2 + b) * S_LEN * EMB;
    #pragma unroll
    for (int qs = 0; qs < 4; ++qs)
        #pragma unroll
        for (int ds = 0; ds < 4; ++ds)
            #pragma unroll
            for (int r = 0; r < 4; ++r)
                op[(size_t)(q0 + qs * 16 + l4 * 4 + r) * EMB + h * 64 + ds * 16 + l15] =
                    f2bf(o[qs][ds][r]);
}

// ---------------------------------------------------------------------------
// K2b: merge the 4 k-quarter partials -> AO[b*2048+s][e] bf16
// ---------------------------------------------------------------------------
__global__ __launch_bounds__(256) void k_merge4(
    const unsigned short* __restrict__ Op, unsigned short* __restrict__ AO)
{
    const size_t i = ((size_t)blockIdx.x * 256 + threadIdx.x) * 8;
    const size_t row = i >> 10;                 // 0..4095
    const int b = (int)(row >> 11);
    const size_t off = (row & 2047) * EMB + (i & 1023);
    float a0 = 0, a1 = 0, a2 = 0, a3 = 0, a4 = 0, a5 = 0, a6 = 0, a7 = 0;
    #pragma unroll
    for (int kq = 0; kq < 4; ++kq) {
        uint4 u = *(const uint4*)(Op + (size_t)(kq * 2 + b) * S_LEN * EMB + off);
        a0 += bflo(u.x); a1 += bfhi(u.x);
        a2 += bflo(u.y); a3 += bfhi(u.y);
        a4 += bflo(u.z); a5 += bfhi(u.z);
        a6 += bflo(u.w); a7 += bfhi(u.w);
    }
    uint4 r;
    r.x = cvtpk(a0, a1); r.y = cvtpk(a2, a3);
    r.z = cvtpk(a4, a5); r.w = cvtpk(a6, a7);
    *(uint4*)(AO + i) = r;
}

// ---------------------------------------------------------------------------
// K4: out = AO @ W_fc^T + b_fc   (M=4096, N=1024, K=1024), fp32 out.
// Wave = 32 m-rows x 64 n-cols: 2 A-loads share each set of 4 B-loads.
// ---------------------------------------------------------------------------
__global__ __launch_bounds__(256) void k_fc(
    const unsigned short* __restrict__ AO, const unsigned short* __restrict__ Wb,
    const float* __restrict__ bias, float* __restrict__ out)
{
    const int t = threadIdx.x, wave = t >> 6, lane = t & 63;
    const int l15 = lane & 15, l4 = lane >> 4;
    const int m0 = blockIdx.x * 128 + wave * 32;
    const int n0 = blockIdx.y * 64;
    v4f c[2][4];
    #pragma unroll
    for (int i = 0; i < 2; ++i)
        #pragma unroll
        for (int j = 0; j < 4; ++j) c[i][j] = (v4f){0.f, 0.f, 0.f, 0.f};
    for (int k = 0; k < EMB; k += 32) {
        v8s a0 = *(const v8s*)(AO + (size_t)(m0 + l15) * EMB + k + l4 * 8);
        v8s a1 = *(const v8s*)(AO + (size_t)(m0 + 16 + l15) * EMB + k + l4 * 8);
        #pragma unroll
        for (int ns = 0; ns < 4; ++ns) {
            v8s bw = *(const v8s*)(Wb + (size_t)(n0 + ns * 16 + l15) * EMB + k + l4 * 8);
            c[0][ns] = __builtin_amdgcn_mfma_f32_16x16x32_bf16(a0, bw, c[0][ns], 0, 0, 0);
            c[1][ns] = __builtin_amdgcn_mfma_f32_16x16x32_bf16(a1, bw, c[1][ns], 0, 0, 0);
        }
    }
    #pragma unroll
    for (int ms = 0; ms < 2; ++ms)
        #pragma unroll
        for (int ns = 0; ns < 4; ++ns) {
            const float bv = bias[n0 + ns * 16 + l15];
            #pragma unroll
            for (int r = 0; r < 4; ++r)
                out[(size_t)(m0 + ms * 16 + l4 * 4 + r) * EMB + n0 + ns * 16 + l15] = c[ms][ns][r] + bv;
        }
}

extern "C" void kernel_launch(void* const* d_in, const int* in_sizes, int n_in,
                              void* d_out, int out_size, void* d_ws, size_t ws_size,
                              hipStream_t stream)
{
    (void)in_sizes; (void)n_in; (void)out_size; (void)ws_size;
    const float* q   = (const float*)d_in[0];
    const float* k   = (const float*)d_in[1];
    const float* v   = (const float*)d_in[2];
    const float* Wq  = (const float*)d_in[3];
    const float* Wk  = (const float*)d_in[4];
    const float* Wv  = (const float*)d_in[5];
    const float* Wfc = (const float*)d_in[6];
    const float* bfc = (const float*)d_in[7];

    char* w = (char*)d_ws;
    unsigned short* Qp = (unsigned short*)(w);                      //  8 MiB (AO overlays after k_fattn)
    unsigned short* Kp = (unsigned short*)(w + (8u  << 20));        //  8 MiB
    unsigned short* Vt = (unsigned short*)(w + (16u << 20));        //  8 MiB
    unsigned short* Wb = (unsigned short*)(w + (24u << 20));        //  2 MiB
    unsigned short* Op = (unsigned short*)(w + (26u << 20));        // 32 MiB (8 planes)
    unsigned short* AO = Qp;                                        // reuse (Qp dead post-attn)

    k_proj2 <<<dim3(128, 3, 4), dim3(128),  0, stream>>>(q, k, v, Wq, Wk, Wv, Qp, Kp, Vt);
    k_cvtw  <<<dim3(1024),      dim3(256),  0, stream>>>(Wfc, Wb);
    k_fattn <<<dim3(256),       dim3(1024), 0, stream>>>(Qp, Kp, Vt, Op);
    k_merge4<<<dim3(2048),      dim3(256),  0, stream>>>(Op, AO);
    k_fc    <<<dim3(32, 16),    dim3(256),  0, stream>>>(AO, Wb, bfc, (float*)d_out);
}